// Round 2
// baseline (190.315 us; speedup 1.0000x reference)
//
#include <hip/hip_runtime.h>
#include <stdint.h>

#define DEV __device__ __forceinline__

typedef float f32x4 __attribute__((ext_vector_type(4)));
typedef __bf16 bf16x8 __attribute__((ext_vector_type(8)));
typedef short short8 __attribute__((ext_vector_type(8)));
typedef short short4v __attribute__((ext_vector_type(4)));

DEV unsigned short f2bf(float f) {
    union { float f; unsigned u; } c; c.f = f;
    unsigned u = c.u;
    u += 0x7fffu + ((u >> 16) & 1u);   // round-to-nearest-even
    return (unsigned short)(u >> 16);
}
DEV void async_ld16(const void* g, void* l) {
    __builtin_amdgcn_global_load_lds(
        (const __attribute__((address_space(1))) unsigned int*)g,
        (__attribute__((address_space(3))) unsigned int*)l, 16, 0, 0);
}
DEV f32x4 mfma16(bf16x8 a, bf16x8 b, f32x4 c) {
    return __builtin_amdgcn_mfma_f32_16x16x32_bf16(a, b, c, 0, 0, 0);
}

// ---------------- k_prep: x->bf16 + W de-interleaved transpose --------------
// blocks [0,4096): x cvt; [4096,4864): W -> Wt[3][1024][1024]
__global__ __launch_bounds__(256) void k_prep(const float* __restrict__ x,
                                              const float* __restrict__ W,
                                              unsigned short* __restrict__ xb,
                                              unsigned short* __restrict__ Wt) {
    __shared__ float T[64][65];
    const int blk = blockIdx.x, t = threadIdx.x;
    if (blk < 4096) {
        int i = blk * 256 + t;
        const float4* xp = (const float4*)x;
        float4 a = xp[i * 2], b = xp[i * 2 + 1];
        short8 o;
        o[0] = (short)f2bf(a.x); o[1] = (short)f2bf(a.y);
        o[2] = (short)f2bf(a.z); o[3] = (short)f2bf(a.w);
        o[4] = (short)f2bf(b.x); o[5] = (short)f2bf(b.y);
        o[6] = (short)f2bf(b.z); o[7] = (short)f2bf(b.w);
        *(short8*)(xb + i * 8) = o;
    } else {
        int bx = blk - 4096;
        int k0 = (bx / 48) * 64, n0 = (bx % 48) * 64;
        int rr = t >> 4, c4 = (t & 15) * 4;
        for (int i = 0; i < 4; i++) {
            int row = rr + i * 16;
            float4 v = *(const float4*)(W + (unsigned)(k0 + row) * 3072u + n0 + c4);
            T[row][c4] = v.x; T[row][c4 + 1] = v.y; T[row][c4 + 2] = v.z; T[row][c4 + 3] = v.w;
        }
        __syncthreads();
        for (int i = 0; i < 4; i++) {
            int ncol = rr + i * 16;
            int n = n0 + ncol;
            int which = n % 3;
            int oc = (n / 192) * 64 + (n % 192) / 3;
            short4v o;
            o[0] = (short)f2bf(T[c4 + 0][ncol]);
            o[1] = (short)f2bf(T[c4 + 1][ncol]);
            o[2] = (short)f2bf(T[c4 + 2][ncol]);
            o[3] = (short)f2bf(T[c4 + 3][ncol]);
            *(short4v*)(Wt + (unsigned)which * 1048576u + (unsigned)oc * 1024u + k0 + c4) = o;
        }
    }
}

// ---------------- k_qkv: combined QKV projection ----------------------------
// BM=256 tokens x BN=128 outcols, BK=64. 512 thr = 8 waves (4M x 2N, 64x64).
// 3 LDS buffers, 2-tile-deep global_load_lds prefetch, counted vmcnt (never
// drained in steady state), raw s_barrier. Grid 32x24 = 768 = 3 perfect
// rounds. Plane 0 (Q) swaps MFMA operands so acc regs = 4 consecutive cols
// (packed Qs stores); planes 1/2 keep A=tokens so acc regs = 4 consecutive
// tokens (packed transposed K/V stores). XCD-bijective block swizzle.
#define BARRIER() asm volatile("s_barrier" ::: "memory")
#define WAITV(n) do { asm volatile("s_waitcnt vmcnt(" #n ")" ::: "memory"); \
                      __builtin_amdgcn_sched_barrier(0); } while (0)

__global__ __launch_bounds__(512, 2) void k_qkv(const unsigned short* __restrict__ xb,
                                                const unsigned short* __restrict__ Wt,
                                                const float* __restrict__ bias,
                                                unsigned short* __restrict__ Qs,
                                                unsigned short* __restrict__ K,
                                                unsigned short* __restrict__ V) {
    __shared__ __align__(16) unsigned short As[3][256 * 64];   // 96KB
    __shared__ __align__(16) unsigned short Bs[3][128 * 64];   // 48KB

    // XCD-contiguous bijective remap (768 % 8 == 0)
    const int o = blockIdx.x + 24 * blockIdx.y;
    const int w = (o & 7) * 96 + (o >> 3);
    const int mt = w / 24, nt = w % 24;
    const int m0 = mt * 256;                 // token base
    const int plane = nt >> 3;               // 0=Q 1=K 2=V
    const int pc0 = (nt & 7) * 128;          // col base within plane
    const unsigned short* Xp = xb + (unsigned)m0 * 1024u;
    const unsigned short* Wp = Wt + (unsigned)plane * 1048576u + (unsigned)pc0 * 1024u;

    const int t = threadIdx.x;
    const int wave = t >> 6, lane = t & 63;
    const int lan15 = lane & 15, quad = lane >> 4;
    const int srow = t >> 3;                 // staging row-in-round (0..63)
    const int schunk = t & 7;                // staging 16B chunk (0..7)

    // operand roles: plane 0 swapped (A = W cols), else A = tokens
    const bool swp = (plane == 0);
    const int ga = swp ? (wave & 1) : (wave >> 1);   // A-side 64-row group
    const int gb = swp ? (wave >> 1) : (wave & 1);   // B-side 64-row group

    f32x4 acc[4][4] = {};

#define STAGE(kt, b) do {                                                     \
        const int kk_ = (kt) * 64;                                            \
        _Pragma("unroll")                                                     \
        for (int i_ = 0; i_ < 4; i_++) {                                      \
            int r_ = i_ * 64 + srow;                                          \
            int c_ = schunk ^ (r_ & 7);                                       \
            async_ld16(Xp + (unsigned)r_ * 1024u + kk_ + c_ * 8,              \
                       (void*)(As[b] + (i_ * 64 + wave * 8) * 64));           \
        }                                                                     \
        _Pragma("unroll")                                                     \
        for (int i_ = 0; i_ < 2; i_++) {                                      \
            int r_ = i_ * 64 + srow;                                          \
            int c_ = schunk ^ (r_ & 7);                                       \
            async_ld16(Wp + (unsigned)r_ * 1024u + kk_ + c_ * 8,              \
                       (void*)(Bs[b] + (i_ * 64 + wave * 8) * 64));           \
        }                                                                     \
    } while (0)

    STAGE(0, 0);
    STAGE(1, 1);

    for (int kt = 0; kt < 16; kt++) {
        const int buf = kt % 3;
        if (kt + 2 < 16) {
            STAGE(kt + 2, (kt + 2) % 3);
            WAITV(12);                       // tile kt landed
        } else if (kt + 1 < 16) {
            WAITV(6);
        } else {
            WAITV(0);
        }
        BARRIER();

        const unsigned short* Ab = (swp ? Bs[buf] : As[buf]) + ga * 64 * 64;
        const unsigned short* Bb = (swp ? As[buf] : Bs[buf]) + gb * 64 * 64;
#pragma unroll
        for (int ks = 0; ks < 2; ks++) {
            const int c0 = ks * 4 + quad;
            bf16x8 af[4], bfr[4];
#pragma unroll
            for (int tm = 0; tm < 4; tm++) {
                int row = tm * 16 + lan15;
                af[tm] = *(const bf16x8*)(Ab + row * 64 + (c0 ^ (row & 7)) * 8);
            }
#pragma unroll
            for (int tn = 0; tn < 4; tn++) {
                int row = tn * 16 + lan15;
                bfr[tn] = *(const bf16x8*)(Bb + row * 64 + (c0 ^ (row & 7)) * 8);
            }
            __builtin_amdgcn_s_setprio(1);
#pragma unroll
            for (int tm = 0; tm < 4; tm++)
#pragma unroll
                for (int tn = 0; tn < 4; tn++)
                    acc[tm][tn] = mfma16(af[tm], bfr[tn], acc[tm][tn]);
            __builtin_amdgcn_s_setprio(0);
        }
        BARRIER();
    }
#undef STAGE

    if (plane == 0) {
        // acc[tm][*]: tm/quad/reg = outcol; tn/lan15 = token
        const int cg = (wave & 1) * 64, tg = (wave >> 1) * 64;
#pragma unroll
        for (int tm = 0; tm < 4; tm++) {
            int c4 = pc0 + cg + tm * 16 + quad * 4;   // 4-aligned, within one head
            int h = c4 >> 6, dd = c4 & 63;
            float b0 = bias[h * 192 + (dd + 0) * 3];
            float b1 = bias[h * 192 + (dd + 1) * 3];
            float b2 = bias[h * 192 + (dd + 2) * 3];
            float b3 = bias[h * 192 + (dd + 3) * 3];
#pragma unroll
            for (int tn = 0; tn < 4; tn++) {
                int token = m0 + tg + tn * 16 + lan15;
                unsigned bb = (unsigned)(token >> 11), tl = (unsigned)(token & 2047);
                uint2 p;
                p.x = (unsigned)f2bf((acc[tm][tn][0] + b0) * 32.0f) |
                      ((unsigned)f2bf((acc[tm][tn][1] + b1) * 32.0f) << 16);
                p.y = (unsigned)f2bf((acc[tm][tn][2] + b2) * 32.0f) |
                      ((unsigned)f2bf((acc[tm][tn][3] + b3) * 32.0f) << 16);
                *(uint2*)(Qs + bb * 2097152u + tl * 1024u + c4) = p;
            }
        }
    } else {
        // acc[tm][*]: tm/quad/reg = token; tn/lan15 = KV col
        unsigned short* dst = (plane == 1) ? K : V;
        const int tg = (wave >> 1) * 64, cg = (wave & 1) * 64;
        const int batch = m0 >> 11;
#pragma unroll
        for (int tn = 0; tn < 4; tn++) {
            int cip = pc0 + cg + tn * 16 + lan15;     // col in plane
            int h = cip >> 6, d = cip & 63;
            float bv = bias[h * 192 + d * 3 + plane];
            unsigned kv_base = ((unsigned)(batch * 16 + h) * 64u + (unsigned)d) * 2048u;
#pragma unroll
            for (int tm = 0; tm < 4; tm++) {
                unsigned token0 = (unsigned)((m0 + tg + tm * 16 + quad * 4) & 2047);
                uint2 p;
                p.x = (unsigned)f2bf(acc[tm][tn][0] + bv) |
                      ((unsigned)f2bf(acc[tm][tn][1] + bv) << 16);
                p.y = (unsigned)f2bf(acc[tm][tn][2] + bv) |
                      ((unsigned)f2bf(acc[tm][tn][3] + bv) << 16);
                *(uint2*)(dst + kv_base + token0) = p;
            }
        }
    }
}

// ---------------- k_attn4: redundant M = K^T V (async-staged), out = Q.M ----
// grid 512: bh = blockIdx & 63 (XCD swizzle), sub = blockIdx >> 6.
__global__ __launch_bounds__(256) void k_attn4(const unsigned short* __restrict__ Kt,
                                               const unsigned short* __restrict__ Vt,
                                               const unsigned short* __restrict__ Qs,
                                               float* __restrict__ out) {
    __shared__ __align__(16) unsigned short Ks[64 * 128];   // 16KB [d][tok]
    __shared__ __align__(16) unsigned short Vs[64 * 128];   // 16KB [d][tok]
    __shared__ __align__(16) unsigned short Msb[64 * 64];   // 8KB [d2][d1]
    const int bh = blockIdx.x & 63, sub = blockIdx.x >> 6;
    const int b = bh >> 4, h = bh & 15;
    const int wave = threadIdx.x >> 6, lane = threadIdx.x & 63;
    const int lan15 = lane & 15, quad = lane >> 4;
    const unsigned base = (unsigned)bh * 131072u;
    const int mt0 = (wave & 1) * 2, nt0 = (wave >> 1) * 2;   // wave's 2x2 tiles
    const int slr = wave * 16 + (lane >> 4), scs = lane & 15;

    f32x4 macc[2][2] = {};
    for (int j = 0; j < 16; j++) {
        __syncthreads();
        for (int i = 0; i < 4; i++) {
            int lr = slr + i * 4;
            int c = scs ^ (lr & 15);
            async_ld16(Kt + base + (unsigned)lr * 2048u + j * 128 + c * 8,
                       (void*)(Ks + (wave * 16 + i * 4) * 128));
            async_ld16(Vt + base + (unsigned)lr * 2048u + j * 128 + c * 8,
                       (void*)(Vs + (wave * 16 + i * 4) * 128));
        }
        __syncthreads();
        for (int ks2 = 0; ks2 < 4; ks2++) {
            int c0 = ks2 * 4 + quad;
            bf16x8 ak[2], bv[2];
            for (int i = 0; i < 2; i++) {
                int row = (mt0 + i) * 16 + lan15;
                ak[i] = *(const bf16x8*)(Ks + row * 128 + (c0 ^ (row & 15)) * 8);
            }
            for (int i = 0; i < 2; i++) {
                int row = (nt0 + i) * 16 + lan15;
                bv[i] = *(const bf16x8*)(Vs + row * 128 + (c0 ^ (row & 15)) * 8);
            }
            for (int i = 0; i < 2; i++)
                for (int j2 = 0; j2 < 2; j2++)
                    macc[i][j2] = mfma16(ak[i], bv[j2], macc[i][j2]);
        }
    }
    // write M tiles: lane holds d1 = (mt0+i)*16 + quad*4 + r, d2 = (nt0+j2)*16+lan15
    for (int i = 0; i < 2; i++)
        for (int j2 = 0; j2 < 2; j2++) {
            int d2 = (nt0 + j2) * 16 + lan15;
            int c4 = ((mt0 + i) * 4 + quad) ^ (d2 & 15);
            uint2 p;
            p.x = (unsigned)f2bf(macc[i][j2][0]) | ((unsigned)f2bf(macc[i][j2][1]) << 16);
            p.y = (unsigned)f2bf(macc[i][j2][2]) | ((unsigned)f2bf(macc[i][j2][3]) << 16);
            *(uint2*)(Msb + d2 * 64 + c4 * 4) = p;
        }
    __syncthreads();

    // ---- phase B: out rows [sub*256 + wave*64, +64) = Q . M ----
    const int t0 = sub * 256 + wave * 64;
    f32x4 oacc[4][4] = {};
#pragma unroll
    for (int ks = 0; ks < 2; ks++) {
        bf16x8 af[4], bfr[4];
        for (int mt = 0; mt < 4; mt++) {
            int tok = t0 + mt * 16 + lan15;
            af[mt] = *(const bf16x8*)(Qs + (unsigned)b * 2097152u + (unsigned)tok * 1024u +
                                      h * 64 + ks * 32 + quad * 8);
        }
        for (int nt = 0; nt < 4; nt++) {
            int d2 = nt * 16 + lan15;
            int cA = ks * 8 + quad * 2;
            uint2 u0 = *(const uint2*)(Msb + d2 * 64 + ((cA) ^ (d2 & 15)) * 4);
            uint2 u1 = *(const uint2*)(Msb + d2 * 64 + ((cA + 1) ^ (d2 & 15)) * 4);
            union { uint4 u; bf16x8 v; } cv;
            cv.u.x = u0.x; cv.u.y = u0.y; cv.u.z = u1.x; cv.u.w = u1.y;
            bfr[nt] = cv.v;
        }
        for (int mt = 0; mt < 4; mt++)
            for (int nt = 0; nt < 4; nt++)
                oacc[mt][nt] = mfma16(af[mt], bfr[nt], oacc[mt][nt]);
    }
    for (int mt = 0; mt < 4; mt++)
        for (int nt = 0; nt < 4; nt++)
            for (int r = 0; r < 4; r++)
                out[base + (unsigned)(t0 + mt * 16 + quad * 4 + r) * 64u + nt * 16 + lan15] =
                    oacc[mt][nt][r];
}

extern "C" void kernel_launch(void* const* d_in, const int* in_sizes, int n_in,
                              void* d_out, int out_size, void* d_ws, size_t ws_size,
                              hipStream_t stream) {
    const float* x = (const float*)d_in[0];
    const float* W = (const float*)d_in[1];
    const float* b = (const float*)d_in[2];
    float* out = (float*)d_out;

    unsigned short* xb = (unsigned short*)d_ws;  // 8,388,608  [8192][1024] bf16
    unsigned short* Wt = xb + 8388608;           // 3,145,728  [3][1024][1024] bf16
    unsigned short* Qs = Wt + 3145728;           // 8,388,608  [4][2048][1024] bf16 (*32,+bias)
    unsigned short* Kt = Qs + 8388608;           // 8,388,608  [bh][d][n] bf16 (+bias)
    unsigned short* Vt = Kt + 8388608;           // 8,388,608  [bh][d][n] bf16 (+bias)
    // total: 73,400,320 bytes (known-safe)

    k_prep<<<4864, 256, 0, stream>>>(x, W, xb, Wt);
    k_qkv<<<dim3(24, 32), 512, 0, stream>>>(xb, Wt, b, Qs, Kt, Vt);
    k_attn4<<<512, 256, 0, stream>>>(Kt, Vt, Qs, out);
}

// Round 3
// 181.972 us; speedup vs baseline: 1.0458x; 1.0458x over previous
//
#include <hip/hip_runtime.h>
#include <stdint.h>

#define DEV __device__ __forceinline__

typedef float f32x4 __attribute__((ext_vector_type(4)));
typedef __bf16 bf16x8 __attribute__((ext_vector_type(8)));
typedef short short8 __attribute__((ext_vector_type(8)));
typedef short short4v __attribute__((ext_vector_type(4)));

DEV unsigned short f2bf(float f) {
    union { float f; unsigned u; } c; c.f = f;
    unsigned u = c.u;
    u += 0x7fffu + ((u >> 16) & 1u);   // round-to-nearest-even
    return (unsigned short)(u >> 16);
}
DEV void async_ld16(const void* g, void* l) {
    __builtin_amdgcn_global_load_lds(
        (const __attribute__((address_space(1))) unsigned int*)g,
        (__attribute__((address_space(3))) unsigned int*)l, 16, 0, 0);
}
DEV f32x4 mfma16(bf16x8 a, bf16x8 b, f32x4 c) {
    return __builtin_amdgcn_mfma_f32_16x16x32_bf16(a, b, c, 0, 0, 0);
}

// ---------------- k_prep: x->bf16 + W de-interleaved transpose --------------
// blocks [0,4096): x cvt; [4096,4864): W -> Wt[3][1024][1024]
__global__ __launch_bounds__(256) void k_prep(const float* __restrict__ x,
                                              const float* __restrict__ W,
                                              unsigned short* __restrict__ xb,
                                              unsigned short* __restrict__ Wt) {
    __shared__ float T[64][65];
    const int blk = blockIdx.x, t = threadIdx.x;
    if (blk < 4096) {
        int i = blk * 256 + t;
        const float4* xp = (const float4*)x;
        float4 a = xp[i * 2], b = xp[i * 2 + 1];
        short8 o;
        o[0] = (short)f2bf(a.x); o[1] = (short)f2bf(a.y);
        o[2] = (short)f2bf(a.z); o[3] = (short)f2bf(a.w);
        o[4] = (short)f2bf(b.x); o[5] = (short)f2bf(b.y);
        o[6] = (short)f2bf(b.z); o[7] = (short)f2bf(b.w);
        *(short8*)(xb + i * 8) = o;
    } else {
        int bx = blk - 4096;
        int k0 = (bx / 48) * 64, n0 = (bx % 48) * 64;
        int rr = t >> 4, c4 = (t & 15) * 4;
        for (int i = 0; i < 4; i++) {
            int row = rr + i * 16;
            float4 v = *(const float4*)(W + (unsigned)(k0 + row) * 3072u + n0 + c4);
            T[row][c4] = v.x; T[row][c4 + 1] = v.y; T[row][c4 + 2] = v.z; T[row][c4 + 3] = v.w;
        }
        __syncthreads();
        for (int i = 0; i < 4; i++) {
            int ncol = rr + i * 16;
            int n = n0 + ncol;
            int which = n % 3;
            int oc = (n / 192) * 64 + (n % 192) / 3;
            short4v o;
            o[0] = (short)f2bf(T[c4 + 0][ncol]);
            o[1] = (short)f2bf(T[c4 + 1][ncol]);
            o[2] = (short)f2bf(T[c4 + 2][ncol]);
            o[3] = (short)f2bf(T[c4 + 3][ncol]);
            *(short4v*)(Wt + (unsigned)which * 1048576u + (unsigned)oc * 1024u + k0 + c4) = o;
        }
    }
}

// ---------------- k_qkv: combined QKV projection ----------------------------
// BM=128 tokens x BN=128 outcols, BK=64. 256 thr = 4 waves (2x2 of 64x64).
// 2 LDS buffers (64KB -> 2 blocks/CU), 1-deep global_load_lds prefetch,
// counted vmcnt (8 in steady state, never full drain), raw s_barrier.
// Grid 1536 = 6 blocks/CU = 3 residency rounds of 2. Plane 0 (Q) swaps MFMA
// operands so acc regs = 4 consecutive outcols (packed Qs stores); planes
// 1/2 keep A=tokens so acc regs = 4 consecutive tokens (packed transposed
// K/V stores). XCD-bijective block swizzle (1536 % 8 == 0).
#define BARRIER() asm volatile("s_barrier" ::: "memory")
#define WAITV(n) do { asm volatile("s_waitcnt vmcnt(" #n ")" ::: "memory"); \
                      __builtin_amdgcn_sched_barrier(0); } while (0)

__global__ __launch_bounds__(256, 2) void k_qkv(const unsigned short* __restrict__ xb,
                                                const unsigned short* __restrict__ Wt,
                                                const float* __restrict__ bias,
                                                unsigned short* __restrict__ Qs,
                                                unsigned short* __restrict__ K,
                                                unsigned short* __restrict__ V) {
    __shared__ __align__(16) unsigned short As[2][128 * 64];   // 32KB (X tokens)
    __shared__ __align__(16) unsigned short Bs[2][128 * 64];   // 32KB (W cols)

    // XCD-contiguous bijective remap (1536 % 8 == 0)
    const int o = blockIdx.x;
    const int w = (o & 7) * 192 + (o >> 3);
    const int mt = w / 24, nt = w % 24;
    const int m0 = mt * 128;                 // token base
    const int plane = nt >> 3;               // 0=Q 1=K 2=V
    const int pc0 = (nt & 7) * 128;          // col base within plane
    const unsigned short* Xp = xb + (unsigned)m0 * 1024u;
    const unsigned short* Wp = Wt + (unsigned)plane * 1048576u + (unsigned)pc0 * 1024u;

    const int t = threadIdx.x;
    const int wave = t >> 6, lane = t & 63;
    const int lan15 = lane & 15, quad = lane >> 4;
    const int slr = wave * 32 + (lane >> 3);  // staging row
    const int scs = lane & 7;                 // staging 16B chunk

    // operand roles: plane 0 swapped (A = W cols), else A = tokens
    const bool swp = (plane == 0);
    const int aw = (wave & 1) * 64;           // A-side 64-row group
    const int bw = (wave >> 1) * 64;          // B-side 64-row group

    f32x4 acc[4][4] = {};

#define STAGE(kt, b) do {                                                     \
        const int kk_ = (kt) * 64;                                            \
        _Pragma("unroll")                                                     \
        for (int i_ = 0; i_ < 4; i_++) {                                      \
            int r_ = slr + i_ * 8;                                            \
            int c_ = scs ^ (r_ & 7);                                          \
            async_ld16(Xp + (unsigned)r_ * 1024u + kk_ + c_ * 8,              \
                       (void*)(As[b] + (wave * 32 + i_ * 8) * 64));           \
            async_ld16(Wp + (unsigned)r_ * 1024u + kk_ + c_ * 8,              \
                       (void*)(Bs[b] + (wave * 32 + i_ * 8) * 64));           \
        }                                                                     \
    } while (0)

    STAGE(0, 0);

    for (int kt = 0; kt < 16; kt++) {
        const int buf = kt & 1;
        if (kt + 1 < 16) {
            STAGE(kt + 1, buf ^ 1);
            WAITV(8);                        // tile kt landed; kt+1 in flight
        } else {
            WAITV(0);
        }
        BARRIER();

        const unsigned short* Ab = (swp ? Bs[buf] : As[buf]) + aw * 64;
        const unsigned short* Bb = (swp ? As[buf] : Bs[buf]) + bw * 64;
#pragma unroll
        for (int ks = 0; ks < 2; ks++) {
            const int c0 = ks * 4 + quad;
            bf16x8 af[4], bfr[4];
#pragma unroll
            for (int tm = 0; tm < 4; tm++) {
                int row = tm * 16 + lan15;
                af[tm] = *(const bf16x8*)(Ab + row * 64 + (c0 ^ (row & 7)) * 8);
            }
#pragma unroll
            for (int tn = 0; tn < 4; tn++) {
                int row = tn * 16 + lan15;
                bfr[tn] = *(const bf16x8*)(Bb + row * 64 + (c0 ^ (row & 7)) * 8);
            }
#pragma unroll
            for (int tm = 0; tm < 4; tm++)
#pragma unroll
                for (int tn = 0; tn < 4; tn++)
                    acc[tm][tn] = mfma16(af[tm], bfr[tn], acc[tm][tn]);
        }
        BARRIER();
    }
#undef STAGE

    if (plane == 0) {
        // acc[tm][*]: tm/quad/reg = outcol; tn/lan15 = token
#pragma unroll
        for (int tm = 0; tm < 4; tm++) {
            int c4 = pc0 + aw + tm * 16 + quad * 4;   // 4-aligned, within one head
            int h = c4 >> 6, dd = c4 & 63;
            float b0 = bias[h * 192 + (dd + 0) * 3];
            float b1 = bias[h * 192 + (dd + 1) * 3];
            float b2 = bias[h * 192 + (dd + 2) * 3];
            float b3 = bias[h * 192 + (dd + 3) * 3];
#pragma unroll
            for (int tn = 0; tn < 4; tn++) {
                int token = m0 + bw + tn * 16 + lan15;
                unsigned bb = (unsigned)(token >> 11), tl = (unsigned)(token & 2047);
                uint2 p;
                p.x = (unsigned)f2bf((acc[tm][tn][0] + b0) * 32.0f) |
                      ((unsigned)f2bf((acc[tm][tn][1] + b1) * 32.0f) << 16);
                p.y = (unsigned)f2bf((acc[tm][tn][2] + b2) * 32.0f) |
                      ((unsigned)f2bf((acc[tm][tn][3] + b3) * 32.0f) << 16);
                *(uint2*)(Qs + bb * 2097152u + tl * 1024u + c4) = p;
            }
        }
    } else {
        // acc[tm][*]: tm/quad/reg = token; tn/lan15 = KV col
        unsigned short* dst = (plane == 1) ? K : V;
        const int batch = m0 >> 11;
#pragma unroll
        for (int tn = 0; tn < 4; tn++) {
            int cip = pc0 + bw + tn * 16 + lan15;     // col in plane
            int h = cip >> 6, d = cip & 63;
            float bv = bias[h * 192 + d * 3 + plane];
            unsigned kv_base = ((unsigned)(batch * 16 + h) * 64u + (unsigned)d) * 2048u;
#pragma unroll
            for (int tm = 0; tm < 4; tm++) {
                unsigned token0 = (unsigned)((m0 + aw + tm * 16 + quad * 4) & 2047);
                uint2 p;
                p.x = (unsigned)f2bf(acc[tm][tn][0] + bv) |
                      ((unsigned)f2bf(acc[tm][tn][1] + bv) << 16);
                p.y = (unsigned)f2bf(acc[tm][tn][2] + bv) |
                      ((unsigned)f2bf(acc[tm][tn][3] + bv) << 16);
                *(uint2*)(dst + kv_base + token0) = p;
            }
        }
    }
}

// ---------------- k_attn4: redundant M = K^T V (async-staged), out = Q.M ----
// grid 512: bh = blockIdx & 63 (XCD swizzle), sub = blockIdx >> 6.
__global__ __launch_bounds__(256) void k_attn4(const unsigned short* __restrict__ Kt,
                                               const unsigned short* __restrict__ Vt,
                                               const unsigned short* __restrict__ Qs,
                                               float* __restrict__ out) {
    __shared__ __align__(16) unsigned short Ks[64 * 128];   // 16KB [d][tok]
    __shared__ __align__(16) unsigned short Vs[64 * 128];   // 16KB [d][tok]
    __shared__ __align__(16) unsigned short Msb[64 * 64];   // 8KB [d2][d1]
    const int bh = blockIdx.x & 63, sub = blockIdx.x >> 6;
    const int b = bh >> 4, h = bh & 15;
    const int wave = threadIdx.x >> 6, lane = threadIdx.x & 63;
    const int lan15 = lane & 15, quad = lane >> 4;
    const unsigned base = (unsigned)bh * 131072u;
    const int mt0 = (wave & 1) * 2, nt0 = (wave >> 1) * 2;   // wave's 2x2 tiles
    const int slr = wave * 16 + (lane >> 4), scs = lane & 15;

    f32x4 macc[2][2] = {};
    for (int j = 0; j < 16; j++) {
        __syncthreads();
        for (int i = 0; i < 4; i++) {
            int lr = slr + i * 4;
            int c = scs ^ (lr & 15);
            async_ld16(Kt + base + (unsigned)lr * 2048u + j * 128 + c * 8,
                       (void*)(Ks + (wave * 16 + i * 4) * 128));
            async_ld16(Vt + base + (unsigned)lr * 2048u + j * 128 + c * 8,
                       (void*)(Vs + (wave * 16 + i * 4) * 128));
        }
        __syncthreads();
        for (int ks2 = 0; ks2 < 4; ks2++) {
            int c0 = ks2 * 4 + quad;
            bf16x8 ak[2], bv[2];
            for (int i = 0; i < 2; i++) {
                int row = (mt0 + i) * 16 + lan15;
                ak[i] = *(const bf16x8*)(Ks + row * 128 + (c0 ^ (row & 15)) * 8);
            }
            for (int i = 0; i < 2; i++) {
                int row = (nt0 + i) * 16 + lan15;
                bv[i] = *(const bf16x8*)(Vs + row * 128 + (c0 ^ (row & 15)) * 8);
            }
            for (int i = 0; i < 2; i++)
                for (int j2 = 0; j2 < 2; j2++)
                    macc[i][j2] = mfma16(ak[i], bv[j2], macc[i][j2]);
        }
    }
    // write M tiles: lane holds d1 = (mt0+i)*16 + quad*4 + r, d2 = (nt0+j2)*16+lan15
    for (int i = 0; i < 2; i++)
        for (int j2 = 0; j2 < 2; j2++) {
            int d2 = (nt0 + j2) * 16 + lan15;
            int c4 = ((mt0 + i) * 4 + quad) ^ (d2 & 15);
            uint2 p;
            p.x = (unsigned)f2bf(macc[i][j2][0]) | ((unsigned)f2bf(macc[i][j2][1]) << 16);
            p.y = (unsigned)f2bf(macc[i][j2][2]) | ((unsigned)f2bf(macc[i][j2][3]) << 16);
            *(uint2*)(Msb + d2 * 64 + c4 * 4) = p;
        }
    __syncthreads();

    // ---- phase B: out rows [sub*256 + wave*64, +64) = Q . M ----
    const int t0 = sub * 256 + wave * 64;
    f32x4 oacc[4][4] = {};
#pragma unroll
    for (int ks = 0; ks < 2; ks++) {
        bf16x8 af[4], bfr[4];
        for (int mt = 0; mt < 4; mt++) {
            int tok = t0 + mt * 16 + lan15;
            af[mt] = *(const bf16x8*)(Qs + (unsigned)b * 2097152u + (unsigned)tok * 1024u +
                                      h * 64 + ks * 32 + quad * 8);
        }
        for (int nt = 0; nt < 4; nt++) {
            int d2 = nt * 16 + lan15;
            int cA = ks * 8 + quad * 2;
            uint2 u0 = *(const uint2*)(Msb + d2 * 64 + ((cA) ^ (d2 & 15)) * 4);
            uint2 u1 = *(const uint2*)(Msb + d2 * 64 + ((cA + 1) ^ (d2 & 15)) * 4);
            union { uint4 u; bf16x8 v; } cv;
            cv.u.x = u0.x; cv.u.y = u0.y; cv.u.z = u1.x; cv.u.w = u1.y;
            bfr[nt] = cv.v;
        }
        for (int mt = 0; mt < 4; mt++)
            for (int nt = 0; nt < 4; nt++)
                oacc[mt][nt] = mfma16(af[mt], bfr[nt], oacc[mt][nt]);
    }
    for (int mt = 0; mt < 4; mt++)
        for (int nt = 0; nt < 4; nt++)
            for (int r = 0; r < 4; r++)
                out[base + (unsigned)(t0 + mt * 16 + quad * 4 + r) * 64u + nt * 16 + lan15] =
                    oacc[mt][nt][r];
}

extern "C" void kernel_launch(void* const* d_in, const int* in_sizes, int n_in,
                              void* d_out, int out_size, void* d_ws, size_t ws_size,
                              hipStream_t stream) {
    const float* x = (const float*)d_in[0];
    const float* W = (const float*)d_in[1];
    const float* b = (const float*)d_in[2];
    float* out = (float*)d_out;

    unsigned short* xb = (unsigned short*)d_ws;  // 8,388,608  [8192][1024] bf16
    unsigned short* Wt = xb + 8388608;           // 3,145,728  [3][1024][1024] bf16
    unsigned short* Qs = Wt + 3145728;           // 8,388,608  [4][2048][1024] bf16 (*32,+bias)
    unsigned short* Kt = Qs + 8388608;           // 8,388,608  [bh][d][n] bf16 (+bias)
    unsigned short* Vt = Kt + 8388608;           // 8,388,608  [bh][d][n] bf16 (+bias)
    // total: 73,400,320 bytes (known-safe)

    k_prep<<<4864, 256, 0, stream>>>(x, W, xb, Wt);
    k_qkv<<<1536, 256, 0, stream>>>(xb, Wt, b, Qs, Kt, Vt);
    k_attn4<<<512, 256, 0, stream>>>(Kt, Vt, Qs, out);
}